// Round 5
// baseline (22.114 us; speedup 1.0000x reference)
//
#include <hip/hip_runtime.h>
#include <hip/hip_bf16.h>
#include <math.h>

#define TPB 256
#define PPT 8  // pred points per thread; TPB*PPT == N == 2048

// Kernel A: block = (batch b, target-chunk tc). Stage tcSize targets in LDS
// as (tx,ty,tz, 0.5*t^2). Each thread owns 8 CONTIGUOUS pred points, loaded
// via 6 float4 loads. Inner loop per 2 targets per point: 6 fma + 1 min3
// (s = 0.5 t^2 - p.t is monotone in d^2). Writes d^2/2 = smin + 0.5 p^2 to
// pmin[tc][b][n] via 2 float4 stores (fully coalesced).
// Block 0 zeroes out[0] for kernel B's atomicAdd accumulation.
__global__ __launch_bounds__(TPB) void chamfer_min_kernel(
    const float* __restrict__ pred, const float* __restrict__ targ,
    float* __restrict__ pmin, float* __restrict__ out, int N, int B, int TC) {
  __shared__ float4 sh[256];
  __shared__ float raw[768];

  const int tc = blockIdx.x % TC;
  const int b = blockIdx.x / TC;
  const int tcSize = N / TC;  // 64 at TC=32 (even, <=256)

  if (blockIdx.x == 0 && threadIdx.x == 0) out[0] = 0.f;  // for B's atomics

  // Stage raw target chunk (float4 vector loads), then build (x,y,z,0.5t^2).
  const float* tb = targ + ((size_t)b * N + (size_t)tc * tcSize) * 3;
  const int nv4 = (tcSize * 3) >> 2;
  for (int i = threadIdx.x; i < nv4; i += TPB)
    ((float4*)raw)[i] = ((const float4*)tb)[i];
  __syncthreads();
  for (int i = threadIdx.x; i < tcSize; i += TPB) {
    const float tx = raw[i * 3 + 0], ty = raw[i * 3 + 1], tz = raw[i * 3 + 2];
    sh[i] = make_float4(tx, ty, tz, 0.5f * (tx * tx + ty * ty + tz * tz));
  }
  __syncthreads();

  // Load this thread's 8 contiguous pred points: 24 floats = 6 float4.
  const int pbase = threadIdx.x * PPT;  // first owned point
  float pf[24];
  {
    const float4* p4 = (const float4*)(pred + (size_t)b * N * 3);
#pragma unroll
    for (int k = 0; k < 6; ++k) {
      const float4 v = p4[threadIdx.x * 6 + k];
      pf[k * 4 + 0] = v.x; pf[k * 4 + 1] = v.y;
      pf[k * 4 + 2] = v.z; pf[k * 4 + 3] = v.w;
    }
  }
  float npx[PPT], npy[PPT], npz[PPT], hp2[PPT], smin[PPT];
#pragma unroll
  for (int j = 0; j < PPT; ++j) {
    const float px = pf[j * 3 + 0], py = pf[j * 3 + 1], pz = pf[j * 3 + 2];
    npx[j] = -px; npy[j] = -py; npz[j] = -pz;
    hp2[j] = 0.5f * (px * px + py * py + pz * pz);
    smin[j] = 3.4e38f;
  }

#pragma unroll 2
  for (int m = 0; m < tcSize; m += 2) {
    const float4 t0 = sh[m];      // broadcast, conflict-free
    const float4 t1 = sh[m + 1];
#pragma unroll
    for (int j = 0; j < PPT; ++j) {
      const float s0 = fmaf(npx[j], t0.x, fmaf(npy[j], t0.y, fmaf(npz[j], t0.z, t0.w)));
      const float s1 = fmaf(npx[j], t1.x, fmaf(npy[j], t1.y, fmaf(npz[j], t1.z, t1.w)));
      smin[j] = fminf(fminf(smin[j], s0), s1);  // -> v_min3_f32
    }
  }

  // Store d^2/2, two float4 per thread (contiguous 8 floats, coalesced).
  float4* dst = (float4*)(pmin + ((size_t)tc * B + b) * N + pbase);
  dst[0] = make_float4(smin[0] + hp2[0], smin[1] + hp2[1],
                       smin[2] + hp2[2], smin[3] + hp2[3]);
  dst[1] = make_float4(smin[4] + hp2[4], smin[5] + hp2[5],
                       smin[6] + hp2[6], smin[7] + hp2[7]);
}

// Kernel B: block = (batch b, 64-point slab). 4 waves split the TC chunks
// 8-way-deep each: per thread 8 INDEPENDENT coalesced loads (256 B per
// wave-load), LDS merge of the 4 per-wave mins, then wave 0 finishes:
// sqrt, asym term, per-point blend, 64-lane shuffle reduce, one
// atomicAdd(out) per block.
__global__ __launch_bounds__(TPB) void chamfer_reduce_kernel(
    const float* __restrict__ pmin, const float* __restrict__ pred,
    const float* __restrict__ targ, const float* __restrict__ sym_flag,
    float* __restrict__ out, int N, int B, int TC, int slabsPerBatch,
    float invNB) {
  const int b = blockIdx.x / slabsPerBatch;
  const int slab = blockIdx.x % slabsPerBatch;
  const int p = threadIdx.x & 63;   // point within slab
  const int g = threadIdx.x >> 6;   // wave id 0..3
  const int tcPer = TC >> 2;        // 8

  const size_t bnStride = (size_t)B * N;
  const size_t base = (size_t)b * N + (size_t)slab * 64 + p;

  float v = 3.4e38f;
#pragma unroll
  for (int k = 0; k < 8; ++k)  // 8 independent coalesced loads
    v = fminf(v, pmin[(size_t)(g * tcPer + k) * bnStride + base]);

  __shared__ float sm[4][64];
  sm[g][p] = v;
  __syncthreads();

  if (threadIdx.x < 64) {
    const float m = fminf(fminf(sm[0][p], sm[1][p]), fminf(sm[2][p], sm[3][p]));
    const float dsym = sqrtf(fmaxf(2.0f * m, 1e-12f));

    const float* pp = pred + base * 3;
    const float* tt = targ + base * 3;
    const float dx = pp[0] - tt[0];
    const float dy = pp[1] - tt[1];
    const float dz = pp[2] - tt[2];
    const float dasym = sqrtf(dx * dx + dy * dy + dz * dz);

    const float f = sym_flag[b];
    float c = (f * dsym + (1.f - f) * dasym) * invNB;
#pragma unroll
    for (int off = 32; off > 0; off >>= 1) c += __shfl_down(c, off);
    if (p == 0) atomicAdd(out, c);
  }
}

extern "C" void kernel_launch(void* const* d_in, const int* in_sizes, int n_in,
                              void* d_out, int out_size, void* d_ws, size_t ws_size,
                              hipStream_t stream) {
  const float* pred = (const float*)d_in[0];
  const float* targ = (const float*)d_in[1];
  const float* sym_flag = (const float*)d_in[2];
  float* out = (float*)d_out;

  const int B = in_sizes[2];            // 16
  const int N = in_sizes[0] / (B * 3);  // 2048

  const int TC = 32;  // pmin = TC*B*N*4 = 4 MB (ws is far larger)
  float* pmin = (float*)d_ws;  // [TC][B][N]

  const int gridA = B * TC;  // 512
  chamfer_min_kernel<<<gridA, TPB, 0, stream>>>(pred, targ, pmin, out, N, B, TC);

  const int slabsPerBatch = N / 64;  // 32
  chamfer_reduce_kernel<<<B * slabsPerBatch, TPB, 0, stream>>>(
      pmin, pred, targ, sym_flag, out, N, B, TC, slabsPerBatch,
      1.0f / (float)(N * B));
}